// Round 1
// baseline (405.881 us; speedup 1.0000x reference)
//
#include <hip/hip_runtime.h>

#define T_STEPS 1024
#define NB 8192
#define OUT_TSTRIDE (8 * NB)   // floats per time step in out[T,8,B]

__device__ __forceinline__ float sigmoidf_(float x) {
    return 1.0f / (1.0f + __expf(-x));
}

// One simulation step. Consumes forcings, updates (snow, soil), stores the
// CH-selected flux to op[TI * 8 * NB].  CH is compile-time -> no select chain.
#define STEP(PR, TM, PE, TI)                                                   \
    do {                                                                       \
        float snowfall    = ((TM) < Tmin) ? (PR) : 0.0f;                       \
        float rainfall    = (PR) - snowfall;                                   \
        float melt        = fminf(snow, Df * fmaxf((TM) - Tmax, 0.0f));        \
        float evap        = (PE) * fminf(soil * rSmax, 1.0f);                  \
        float baseflow    = Qmax * __expf(nf * fmaxf(Smax - soil, 0.0f));      \
        float surfaceflow = fmaxf(soil - Smax, 0.0f);                          \
        float d_snow      = snowfall - melt;                                   \
        float d_soil = (((rainfall + melt) - evap) - baseflow) - surfaceflow;  \
        snow = fmaxf(snow + d_snow, 1e-6f);                                    \
        soil = fmaxf(soil + d_soil, 1e-6f);                                    \
        float sv;                                                              \
        if (CH == 0)      sv = snowfall;                                       \
        else if (CH == 1) sv = rainfall;                                       \
        else if (CH == 2) sv = melt;                                           \
        else if (CH == 3) sv = evap;                                           \
        else if (CH == 4) sv = baseflow;                                       \
        else if (CH == 5) sv = surfaceflow;                                    \
        else if (CH == 6) sv = d_snow;                                         \
        else              sv = d_soil;                                         \
        op[(size_t)(TI) * OUT_TSTRIDE] = sv;                                   \
    } while (0)

template <int CH>
__device__ __forceinline__ void run_basin(const float* __restrict__ pp,
                                          const float* __restrict__ tp,
                                          const float* __restrict__ ep,
                                          float* __restrict__ op, float f,
                                          float Smax, float Qmax, float Df,
                                          float Tmax, float Tmin) {
    const float rSmax = 1.0f / Smax;
    const float nf    = -f;
    float snow = 0.0f, soil = 0.0f;

    // Double-buffered register prefetch: 8 steps per buffer, distance 8-16.
    float Pa[8], Ta[8], Ea[8], Pb[8], Tb[8], Eb[8];
#pragma unroll
    for (int i = 0; i < 8; ++i) {
        Pa[i] = pp[i * NB];
        Ta[i] = tp[i * NB];
        Ea[i] = ep[i * NB];
    }
#pragma unroll
    for (int i = 0; i < 8; ++i) {
        Pb[i] = pp[(8 + i) * NB];
        Tb[i] = tp[(8 + i) * NB];
        Eb[i] = ep[(8 + i) * NB];
    }

    for (int tb = 0; tb < T_STEPS; tb += 16) {
        // compute steps tb..tb+7 out of buffer A
#pragma unroll
        for (int i = 0; i < 8; ++i) STEP(Pa[i], Ta[i], Ea[i], tb + i);
        // refill A with steps tb+16..tb+23 (clamped at the tail; harmless re-read)
#pragma unroll
        for (int i = 0; i < 8; ++i) {
            int t2 = tb + 16 + i;
            t2     = (t2 > T_STEPS - 1) ? (T_STEPS - 1) : t2;
            Pa[i]  = pp[t2 * NB];
            Ta[i]  = tp[t2 * NB];
            Ea[i]  = ep[t2 * NB];
        }
        // compute steps tb+8..tb+15 out of buffer B
#pragma unroll
        for (int i = 0; i < 8; ++i) STEP(Pb[i], Tb[i], Eb[i], tb + 8 + i);
        // refill B with steps tb+24..tb+31 (clamped)
#pragma unroll
        for (int i = 0; i < 8; ++i) {
            int t2 = tb + 24 + i;
            t2     = (t2 > T_STEPS - 1) ? (T_STEPS - 1) : t2;
            Pb[i]  = pp[t2 * NB];
            Tb[i]  = tp[t2 * NB];
            Eb[i]  = ep[t2 * NB];
        }
    }
}

// Grid: 256 blocks = 128 basin-groups x 2 channel-halves.
// Block: 256 threads = 4 waves; wave w stores channel h*4+w.
// All 4 waves recompute the full recurrence for the same 64 basins (cheap);
// forcing loads are identical addresses -> L1 broadcast.
extern "C" __global__ void __launch_bounds__(256, 1)
    hydro_kernel(const float* __restrict__ prcp, const float* __restrict__ temp,
                 const float* __restrict__ pet, const float* __restrict__ spn,
                 float* __restrict__ out) {
    const int lane  = threadIdx.x & 63;
    const int wav   = threadIdx.x >> 6;
    const int h     = blockIdx.x & 1;
    const int g     = blockIdx.x >> 1;
    const int basin = g * 64 + lane;
    const int ch    = h * 4 + wav;

    // Denormalize params: sigmoid then affine to bounds.
    const float* p6  = spn + basin * 6;
    const float f    = 0.1f * sigmoidf_(p6[0]);
    const float Smax = 100.0f + 1400.0f * sigmoidf_(p6[1]);
    const float Qmax = 10.0f + 40.0f * sigmoidf_(p6[2]);
    const float Df   = 5.0f * sigmoidf_(p6[3]);
    const float Tmax = 3.0f * sigmoidf_(p6[4]);
    const float Tmin = -3.0f + 3.0f * sigmoidf_(p6[5]);

    const float* pp = prcp + basin;
    const float* tp = temp + basin;
    const float* ep = pet + basin;
    float* op       = out + (size_t)ch * NB + basin;

    // ch is wave-uniform -> scalar branch, one specialized loop per wave.
    switch (__builtin_amdgcn_readfirstlane(ch)) {
        case 0: run_basin<0>(pp, tp, ep, op, f, Smax, Qmax, Df, Tmax, Tmin); break;
        case 1: run_basin<1>(pp, tp, ep, op, f, Smax, Qmax, Df, Tmax, Tmin); break;
        case 2: run_basin<2>(pp, tp, ep, op, f, Smax, Qmax, Df, Tmax, Tmin); break;
        case 3: run_basin<3>(pp, tp, ep, op, f, Smax, Qmax, Df, Tmax, Tmin); break;
        case 4: run_basin<4>(pp, tp, ep, op, f, Smax, Qmax, Df, Tmax, Tmin); break;
        case 5: run_basin<5>(pp, tp, ep, op, f, Smax, Qmax, Df, Tmax, Tmin); break;
        case 6: run_basin<6>(pp, tp, ep, op, f, Smax, Qmax, Df, Tmax, Tmin); break;
        default: run_basin<7>(pp, tp, ep, op, f, Smax, Qmax, Df, Tmax, Tmin); break;
    }
}

extern "C" void kernel_launch(void* const* d_in, const int* in_sizes, int n_in,
                              void* d_out, int out_size, void* d_ws,
                              size_t ws_size, hipStream_t stream) {
    const float* prcp = (const float*)d_in[0];
    const float* temp = (const float*)d_in[1];
    const float* pet  = (const float*)d_in[2];
    const float* spn  = (const float*)d_in[3];
    float* out        = (float*)d_out;

    hydro_kernel<<<dim3(256), dim3(256), 0, stream>>>(prcp, temp, pet, spn, out);
}